// Round 13
// baseline (37.097 us; speedup 1.0000x reference)
//
#include <hip/hip_runtime.h>

#define Bn 512
#define BC 16    // b rows staged per block; each thread owns bl and bl+8
#define JT 64    // j columns per block
// block: 512 threads = 8 bl x 64 jl, each thread computes 2 (b,j) rows
// grid (32, 8) = 256 blocks; LDS ~35 KB -> 4 blocks/CU -> 32 waves/CU

typedef float v2f __attribute__((ext_vector_type(2)));

__device__ __forceinline__ v2f pk_add(v2f a, v2f b) {
    v2f d; asm("v_pk_add_f32 %0, %1, %2" : "=v"(d) : "v"(a), "v"(b)); return d;
}
__device__ __forceinline__ void pk_acc(v2f& acc, v2f s) {
    asm("v_pk_add_f32 %0, %1, %0" : "+v"(acc) : "v"(s));
}
__device__ __forceinline__ void pk_fma(v2f& acc, v2f a, v2f b) {
    asm("v_pk_fma_f32 %0, %1, %2, %0" : "+v"(acc) : "v"(a), "v"(b));
}

__global__ __launch_bounds__(512, 8) void srap_main(
        const float* __restrict__ scores,
        const float* __restrict__ target,
        float* __restrict__ wsC,
        float* __restrict__ wsT) {
    // transposed, PADDED t-tile: granule (k4,b) at k4*17 + b holds
    // -C*scores[b0+b][4k4..4k4+3]  (padding 17 kills all bank conflicts;
    // address = base + k4*272 B -> pure immediate offsets under unroll)
    __shared__ __align__(16) float sT[128 * 17 * 4];   // ~34.8 KB
    __shared__ float partC[8 * BC], partT[8 * BC];

    const int tid = threadIdx.x;          // 0..511
    const int b0 = blockIdx.x * BC;
    const int j0 = blockIdx.y * JT;
    const int jl = tid >> 3;              // local j (0..63)
    const int bl = tid & 7;               // local b (0..7); also owns bl+8

    const float C = 144.26950408889634f;  // log2(e)/tau, tau = 0.01

    // ---- stage -C*scores[b0..b0+15][0..511] -> sT ----
    {
        const int sr = tid >> 5;          // staged b-row 0..15
        const int sk = tid & 31;          // low k4 bits
        const float4* g4 = (const float4*)(scores + (size_t)(b0 + sr) * Bn);
        #pragma unroll
        for (int i = 0; i < 4; ++i) {
            const int k4 = sk + i * 32;
            float4 v = g4[k4];
            v.x *= -C; v.y *= -C; v.z *= -C; v.w *= -C;
            *(float4*)(&sT[(k4 * 17 + sr) * 4]) = v;
        }
    }
    __syncthreads();

    const int j = j0 + jl;
    const float tj1 = scores[(size_t)(b0 + bl) * Bn + j] * C;
    const float tj2 = scores[(size_t)(b0 + bl + 8) * Bn + j] * C;
    const v2f tja = {tj1, tj1}, tjb = {tj2, tj2};
    const v2f one2 = {1.0f, 1.0f};

    v2f A1a = {0,0}, A1b = {0,0}, A2a = {0,0}, A2b = {0,0};
    v2f P1a = {0,0}, P1b = {0,0}, P2a = {0,0}, P2b = {0,0};

    const float* tb = &sT[bl * 4];
    const float4* tr = (const float4*)(target + (size_t)j * Bn);

    for (int kk = 0; kk < 8; ++kk) {      // 8 chunks x 16 k4
        #pragma unroll
        for (int q = 0; q < 16; ++q) {
            const float4 w  = tr[q];                            // tgt[j,4k..]
            const float4 n1 = *(const float4*)(tb + q * 68);        // -tk (b1)
            const float4 n2 = *(const float4*)(tb + q * 68 + 32);   // -tk (b2)

            v2f n1a, n1b, n2a, n2b, wa, wb;
            __builtin_memcpy(&n1a, &n1.x, 8); __builtin_memcpy(&n1b, &n1.z, 8);
            __builtin_memcpy(&n2a, &n2.x, 8); __builtin_memcpy(&n2b, &n2.z, 8);
            __builtin_memcpy(&wa,  &w.x,  8); __builtin_memcpy(&wb,  &w.z,  8);

            const v2f x1a = pk_add(tja, n1a);   // tj - tk
            const v2f x1b = pk_add(tja, n1b);
            const v2f x2a = pk_add(tjb, n2a);
            const v2f x2b = pk_add(tjb, n2b);

            const v2f e1a = {__builtin_amdgcn_exp2f(x1a[0]), __builtin_amdgcn_exp2f(x1a[1])};
            const v2f e1b = {__builtin_amdgcn_exp2f(x1b[0]), __builtin_amdgcn_exp2f(x1b[1])};
            const v2f e2a = {__builtin_amdgcn_exp2f(x2a[0]), __builtin_amdgcn_exp2f(x2a[1])};
            const v2f e2b = {__builtin_amdgcn_exp2f(x2b[0]), __builtin_amdgcn_exp2f(x2b[1])};

            const v2f d1a = pk_add(e1a, one2);
            const v2f d1b = pk_add(e1b, one2);
            const v2f d2a = pk_add(e2a, one2);
            const v2f d2b = pk_add(e2b, one2);

            const v2f s1a = {__builtin_amdgcn_rcpf(d1a[0]), __builtin_amdgcn_rcpf(d1a[1])};
            const v2f s1b = {__builtin_amdgcn_rcpf(d1b[0]), __builtin_amdgcn_rcpf(d1b[1])};
            const v2f s2a = {__builtin_amdgcn_rcpf(d2a[0]), __builtin_amdgcn_rcpf(d2a[1])};
            const v2f s2b = {__builtin_amdgcn_rcpf(d2b[0]), __builtin_amdgcn_rcpf(d2b[1])};

            pk_acc(A1a, s1a); pk_acc(A1b, s1b);
            pk_acc(A2a, s2a); pk_acc(A2b, s2b);
            pk_fma(P1a, s1a, wa); pk_fma(P1b, s1b, wb);
            pk_fma(P2a, s2a, wa); pk_fma(P2b, s2b, wb);
        }
        tb += 16 * 68;   // 16 k4 * 17 granules * 4 floats
        tr += 16;
    }

    const float A1 = (A1a[0] + A1a[1]) + (A1b[0] + A1b[1]);
    const float A2 = (A2a[0] + A2a[1]) + (A2b[0] + A2b[1]);
    const float P1 = (P1a[0] + P1a[1]) + (P1b[0] + P1b[1]);
    const float P2 = (P2a[0] + P2a[1]) + (P2b[0] + P2b[1]);

    // diag k=j contributes exactly 0.5 to A and P (tgt[j,j]=1, rcp(2)=0.5):
    // sim_all = A + 0.5;  pos = P - 0.5 + target[b,j]
    const float tbj1 = target[(size_t)(b0 + bl) * Bn + j];
    const float tbj2 = target[(size_t)(b0 + bl + 8) * Bn + j];
    float c1 = (P1 - 0.5f + tbj1) * tbj1 / (A1 + 0.5f);
    float c2 = (P2 - 0.5f + tbj2) * tbj2 / (A2 + 0.5f);
    float t1 = tbj1, t2 = tbj2;

    // reduce the 8 jl per wave (wave = 8 jl x 8 bl): lanes 0..7 keep sums
    c1 += __shfl_down(c1, 32); c1 += __shfl_down(c1, 16); c1 += __shfl_down(c1, 8);
    c2 += __shfl_down(c2, 32); c2 += __shfl_down(c2, 16); c2 += __shfl_down(c2, 8);
    t1 += __shfl_down(t1, 32); t1 += __shfl_down(t1, 16); t1 += __shfl_down(t1, 8);
    t2 += __shfl_down(t2, 32); t2 += __shfl_down(t2, 16); t2 += __shfl_down(t2, 8);
    const int wv = tid >> 6;
    if ((tid & 63) < 8) {
        partC[wv * BC + bl]     = c1; partT[wv * BC + bl]     = t1;
        partC[wv * BC + bl + 8] = c2; partT[wv * BC + bl + 8] = t2;
    }
    __syncthreads();

    if (tid < BC) {
        float cs = 0.0f, ts = 0.0f;
        #pragma unroll
        for (int w2 = 0; w2 < 8; ++w2) { cs += partC[w2 * BC + tid]; ts += partT[w2 * BC + tid]; }
        wsC[(size_t)blockIdx.y * Bn + b0 + tid] = cs;
        wsT[(size_t)blockIdx.y * Bn + b0 + tid] = ts;
    }
}

__global__ __launch_bounds__(512) void srap_final(
        const float* __restrict__ wsC, const float* __restrict__ wsT,
        float* __restrict__ out) {
    __shared__ float red[8];
    const int b = threadIdx.x;  // 512 threads, one per batch row
    float num = 0.0f, den = 0.0f;
    #pragma unroll
    for (int jt = 0; jt < Bn / JT; ++jt) {
        num += wsC[jt * Bn + b];
        den += wsT[jt * Bn + b];
    }
    float apb = num / den;
    for (int off = 32; off; off >>= 1) apb += __shfl_down(apb, off);
    if ((b & 63) == 0) red[b >> 6] = apb;
    __syncthreads();
    if (b == 0) {
        float s = 0.0f;
        #pragma unroll
        for (int w = 0; w < 8; ++w) s += red[w];
        out[0] = 1.0f - s * (1.0f / Bn);
    }
}

extern "C" void kernel_launch(void* const* d_in, const int* in_sizes, int n_in,
                              void* d_out, int out_size, void* d_ws, size_t ws_size,
                              hipStream_t stream) {
    const float* scores = (const float*)d_in[0];
    const float* target = (const float*)d_in[1];
    float* out = (float*)d_out;
    float* wsC = (float*)d_ws;                       // 8*512 floats
    float* wsT = wsC + (Bn / JT) * Bn;               // 8*512 floats

    srap_main<<<dim3(Bn / BC, Bn / JT), dim3(512), 0, stream>>>(scores, target, wsC, wsT);
    srap_final<<<dim3(1), dim3(512), 0, stream>>>(wsC, wsT, out);
}